// Round 3
// baseline (786.216 us; speedup 1.0000x reference)
//
#include <hip/hip_runtime.h>

#define BDIM 256
constexpr int Bc = 2048;
constexpr int Nc = 64;
constexpr int Dc = 128;
constexpr int HS = 132;  // LDS row stride in floats: 16B-aligned, bank skew 4
constexpr float NEG_BIG_F = -9.0e15f;
constexpr float INV_SQRT_D = 0.08838834764831845f;  // 1/sqrt(128)

__device__ __forceinline__ float wmax(float v) {
#pragma unroll
    for (int off = 32; off; off >>= 1) v = fmaxf(v, __shfl_xor(v, off, 64));
    return v;
}
__device__ __forceinline__ float wsum(float v) {
#pragma unroll
    for (int off = 32; off; off >>= 1) v += __shfl_xor(v, off, 64);
    return v;
}
__device__ __forceinline__ void fma4(float4& a, float s, const float4& v) {
    a.x = fmaf(s, v.x, a.x);
    a.y = fmaf(s, v.y, a.y);
    a.z = fmaf(s, v.z, a.z);
    a.w = fmaf(s, v.w, a.w);
}

__global__ __launch_bounds__(BDIM) void star_agg_kernel(
    const float* __restrict__ hid,
    const int*   __restrict__ adj,
    const float* __restrict__ maskp,
    const float* __restrict__ a0p, const float* __restrict__ a1p,
    const float* __restrict__ a2p, const float* __restrict__ a3p,
    const float* __restrict__ q1p, const float* __restrict__ k1p,
    const float* __restrict__ q2p, const float* __restrict__ k2p,
    const float* __restrict__ wlp,
    float* __restrict__ outp)
{
    __shared__ float h[Nc][HS];       // sate (fp32 master copy)
    __shared__ float att[Nc][Nc];     // relation logits / attention probs
    __shared__ float aL[4][HS];       // a_0..a_3
    __shared__ float star_s[Dc];
    __shared__ float kk_s[Dc];
    __shared__ float vv_s[Dc];
    __shared__ float m_s[Nc];
    __shared__ float beta_s[Nc];

    const int b    = blockIdx.x;
    const int tid  = threadIdx.x;
    const int lane = tid & 63;
    const int wv   = tid >> 6;

    // ---- loads: hidden -> h (float4), a -> aL, mask -> m_s; zero pad columns
    {
        const float4* hp4 = (const float4*)(hid + (size_t)b * (Nc * Dc));
        for (int idx = tid; idx < (Nc * Dc) / 4; idx += BDIM) {
            const int r = idx >> 5;          // 32 float4 per 128-float row
            const int c = (idx & 31) * 4;
            *(float4*)&h[r][c] = hp4[idx];
        }
        for (int idx = tid; idx < Nc * (HS - Dc); idx += BDIM)   // 256 pad slots
            h[idx >> 2][Dc + (idx & 3)] = 0.f;
        if (tid < 128) {
            const int r = tid >> 5, c4 = tid & 31;
            const float* ap = (r == 0) ? a0p : (r == 1) ? a1p : (r == 2) ? a2p : a3p;
            *(float4*)&aL[r][c4 * 4] = *(const float4*)&ap[c4 * 4];
        }
        if (tid < 16) aL[tid >> 2][Dc + (tid & 3)] = 0.f;        // aL pads
        if (tid < Nc) m_s[tid] = maskp[b * Nc + tid];
    }
    __syncthreads();

    // ---- star init: masked average over nodes
    if (tid < Dc) {
        float s = 0.f, ms = 0.f;
        for (int i = 0; i < Nc; ++i) { s = fmaf(h[i][tid], m_s[i], s); ms += m_s[i]; }
        star_s[tid] = s / ms;
    }
    __syncthreads();

    for (int step = 0; step < 2; ++step) {
        // ---- Phase A: relation logits. Task = (row i, col-group jg); 8 cols
        // j = jg + 8*jj. Select the a-vector per pair, then one dot per pair.
        for (int T = tid; T < 512; T += BDIM) {
            const int i  = T >> 3;
            const int jg = T & 7;
            const float* ap[8];
            bool ok[8];
            float acc[8];
#pragma unroll
            for (int jj = 0; jj < 8; ++jj) {
                const int t = adj[(size_t)b * 4096 + i * 64 + jg + 8 * jj];
                ok[jj]  = (t >= 1 && t <= 4);
                ap[jj]  = aL[ok[jj] ? (t - 1) : 0];
                acc[jj] = 0.f;
            }
            for (int d4 = 0; d4 < 32; ++d4) {
                const float4 hi = *(const float4*)&h[i][d4 * 4];
#pragma unroll
                for (int jj = 0; jj < 8; ++jj) {
                    const float4 hj = *(const float4*)&h[jg + 8 * jj][d4 * 4];
                    const float4 av = *(const float4*)(ap[jj] + d4 * 4);
                    acc[jj] = fmaf(hi.w * hj.w, av.w,
                              fmaf(hi.z * hj.z, av.z,
                              fmaf(hi.y * hj.y, av.y,
                              fmaf(hi.x * hj.x, av.x, acc[jj]))));
                }
            }
#pragma unroll
            for (int jj = 0; jj < 8; ++jj) {
                const float s = acc[jj];
                const float e = ok[jj] ? ((s >= 0.f) ? s : 0.2f * s) : NEG_BIG_F;
                att[i][jg + 8 * jj] = e;
            }
        }
        __syncthreads();

        // ---- softmax over each row of att (wave per row)
        for (int r = 0; r < 16; ++r) {
            const int i = wv * 16 + r;
            const float e  = att[i][lane];
            const float mx = wmax(e);
            const float p  = __expf(e - mx);
            const float sm = wsum(p);
            att[i][lane] = p / sm;
        }
        __syncthreads();

        // ---- Phase B: sate = att @ sate
        {
            const int dg = tid & 31;   // 4-col group
            const int rg = tid >> 5;   // 8 rows each
            float4 acc[8];
#pragma unroll
            for (int r = 0; r < 8; ++r) acc[r] = make_float4(0.f, 0.f, 0.f, 0.f);
            for (int j4 = 0; j4 < 16; ++j4) {
                const float4 hj0 = *(const float4*)&h[j4 * 4 + 0][dg * 4];
                const float4 hj1 = *(const float4*)&h[j4 * 4 + 1][dg * 4];
                const float4 hj2 = *(const float4*)&h[j4 * 4 + 2][dg * 4];
                const float4 hj3 = *(const float4*)&h[j4 * 4 + 3][dg * 4];
#pragma unroll
                for (int r = 0; r < 8; ++r) {
                    const float4 a4 = *(const float4*)&att[rg * 8 + r][j4 * 4];
                    fma4(acc[r], a4.x, hj0);
                    fma4(acc[r], a4.y, hj1);
                    fma4(acc[r], a4.z, hj2);
                    fma4(acc[r], a4.w, hj3);
                }
            }
            __syncthreads();
#pragma unroll
            for (int r = 0; r < 8; ++r)
                *(float4*)&h[rg * 8 + r][dg * 4] = acc[r];
        }
        __syncthreads();

        // ---- kk = star @ k1 ; vv = (q1 @ kk) / sqrt(D)    [alpha_i = sate_i . vv]
        if (tid < Dc) {
            float s = 0.f;
            for (int d = 0; d < Dc; ++d) s = fmaf(star_s[d], k1p[d * Dc + tid], s);
            kk_s[tid] = s;
        }
        __syncthreads();
        if (tid < Dc) {
            float s = 0.f;
            for (int e = 0; e < Dc; ++e) s = fmaf(q1p[tid * Dc + e], kk_s[e], s);
            vv_s[tid] = s * INV_SQRT_D;
        }
        __syncthreads();

        // ---- alpha blend: sate = (1-alpha)*sate + alpha*star
        for (int r = 0; r < 16; ++r) {
            const int i = wv * 16 + r;
            const float part = h[i][lane] * vv_s[lane] + h[i][lane + 64] * vv_s[lane + 64];
            const float al = wsum(part);
            h[i][lane]      = (1.f - al) * h[i][lane]      + al * star_s[lane];
            h[i][lane + 64] = (1.f - al) * h[i][lane + 64] + al * star_s[lane + 64];
        }
        __syncthreads();

        // ---- qq = star @ q2 ; ww = (k2 @ qq) / sqrt(D)    [beta_j = sate_j . ww]
        if (tid < Dc) {
            float s = 0.f;
            for (int d = 0; d < Dc; ++d) s = fmaf(star_s[d], q2p[d * Dc + tid], s);
            kk_s[tid] = s;
        }
        __syncthreads();
        if (tid < Dc) {
            float s = 0.f;
            for (int e = 0; e < Dc; ++e) s = fmaf(k2p[tid * Dc + e], kk_s[e], s);
            vv_s[tid] = s * INV_SQRT_D;
        }
        __syncthreads();

        // ---- beta (masked with finite sentinel; exp(NEG_BIG - mx) == 0 exactly)
        for (int r = 0; r < 16; ++r) {
            const int j = wv * 16 + r;
            const float part = h[j][lane] * vv_s[lane] + h[j][lane + 64] * vv_s[lane + 64];
            const float bj = wsum(part);
            if (lane == 0) beta_s[j] = (m_s[j] == 0.f) ? NEG_BIG_F : bj;
        }
        __syncthreads();

        // ---- star = softmax(beta) @ sate
        if (tid < Dc) {
            float mx = NEG_BIG_F;
            for (int j = 0; j < Nc; ++j) mx = fmaxf(mx, beta_s[j]);
            float sm = 0.f, s = 0.f;
            for (int j = 0; j < Nc; ++j) {
                const float p = __expf(beta_s[j] - mx);
                sm += p;
                s = fmaf(p, h[j][tid], s);
            }
            star_s[tid] = s / sm;
        }
        __syncthreads();
    }

    // ---- star output (second tuple element)
    if (tid < Dc) outp[(size_t)Bc * Nc * Dc + (size_t)b * Dc + tid] = star_s[tid];

    // ---- gate = sigmoid([hidden, sate] @ W_lin^T); out = g*hidden + (1-g)*sate
    // hidden re-read from global (L1/L2-hot); sate from LDS h.
    {
        const int og = tid & 31;
        const int rg = tid >> 5;
        const int o0 = og * 4;
        const float* hrow = hid + (size_t)b * (Nc * Dc);
        float acc[8][4];
#pragma unroll
        for (int r = 0; r < 8; ++r)
#pragma unroll
            for (int oo = 0; oo < 4; ++oo) acc[r][oo] = 0.f;

        // hidden half: c in [0,128)
        for (int c4 = 0; c4 < 32; ++c4) {
            float4 wf[4];
#pragma unroll
            for (int oo = 0; oo < 4; ++oo)
                wf[oo] = *(const float4*)&wlp[(o0 + oo) * 256 + c4 * 4];
#pragma unroll
            for (int r = 0; r < 8; ++r) {
                const float4 hv = *(const float4*)&hrow[(rg * 8 + r) * 128 + c4 * 4];
#pragma unroll
                for (int oo = 0; oo < 4; ++oo)
                    acc[r][oo] = fmaf(hv.w, wf[oo].w, fmaf(hv.z, wf[oo].z,
                                 fmaf(hv.y, wf[oo].y, fmaf(hv.x, wf[oo].x, acc[r][oo]))));
            }
        }
        // sate half: c in [128,256)
        for (int c4 = 0; c4 < 32; ++c4) {
            float4 wf[4];
#pragma unroll
            for (int oo = 0; oo < 4; ++oo)
                wf[oo] = *(const float4*)&wlp[(o0 + oo) * 256 + 128 + c4 * 4];
#pragma unroll
            for (int r = 0; r < 8; ++r) {
                const float4 hv = *(const float4*)&h[rg * 8 + r][c4 * 4];
#pragma unroll
                for (int oo = 0; oo < 4; ++oo)
                    acc[r][oo] = fmaf(hv.w, wf[oo].w, fmaf(hv.z, wf[oo].z,
                                 fmaf(hv.y, wf[oo].y, fmaf(hv.x, wf[oo].x, acc[r][oo]))));
            }
        }
        // finalize + store
#pragma unroll
        for (int r = 0; r < 8; ++r) {
            const int i = rg * 8 + r;
            const float4 hv = *(const float4*)&hrow[i * 128 + o0];
            float4 res;
            {
                const float g0 = 1.f / (1.f + __expf(-acc[r][0]));
                const float g1 = 1.f / (1.f + __expf(-acc[r][1]));
                const float g2 = 1.f / (1.f + __expf(-acc[r][2]));
                const float g3 = 1.f / (1.f + __expf(-acc[r][3]));
                res.x = g0 * hv.x + (1.f - g0) * h[i][o0 + 0];
                res.y = g1 * hv.y + (1.f - g1) * h[i][o0 + 1];
                res.z = g2 * hv.z + (1.f - g2) * h[i][o0 + 2];
                res.w = g3 * hv.w + (1.f - g3) * h[i][o0 + 3];
            }
            *(float4*)&outp[((size_t)b * 64 + i) * 128 + o0] = res;
        }
    }
}

extern "C" void kernel_launch(void* const* d_in, const int* in_sizes, int n_in,
                              void* d_out, int out_size, void* d_ws, size_t ws_size,
                              hipStream_t stream) {
    const float* hid  = (const float*)d_in[0];
    const int*   adj  = (const int*)d_in[1];
    const float* mask = (const float*)d_in[2];
    const float* a0   = (const float*)d_in[3];
    const float* a1   = (const float*)d_in[4];
    const float* a2   = (const float*)d_in[5];
    const float* a3   = (const float*)d_in[6];
    const float* q1   = (const float*)d_in[7];
    const float* k1   = (const float*)d_in[8];
    const float* q2   = (const float*)d_in[9];
    const float* k2   = (const float*)d_in[10];
    const float* wl   = (const float*)d_in[11];
    float* out = (float*)d_out;

    star_agg_kernel<<<Bc, BDIM, 0, stream>>>(hid, adj, mask, a0, a1, a2, a3,
                                             q1, k1, q2, k2, wl, out);
}

// Round 4
// 503.407 us; speedup vs baseline: 1.5618x; 1.5618x over previous
//
#include <hip/hip_runtime.h>

#define BDIM 256
constexpr int Bc = 2048;
constexpr int Nc = 64;
constexpr int Dc = 128;
constexpr float NEG_BIG_F = -9.0e15f;
constexpr float INV_SQRT_D = 0.08838834764831845f;  // 1/sqrt(128)

typedef __attribute__((ext_vector_type(8))) short bf16x8;
typedef __attribute__((ext_vector_type(4))) float f32x4;

#define MFMA16(A, B, C) __builtin_amdgcn_mfma_f32_16x16x32_bf16((A), (B), (C), 0, 0, 0)

__device__ __forceinline__ float bf2f(ushort u) {
    union { float f; unsigned int i; } cv;
    cv.i = ((unsigned int)u) << 16;
    return cv.f;
}
__device__ __forceinline__ ushort f2bf(float f) {
    union { float f; unsigned int i; } cv;
    cv.f = f;
    unsigned int x = cv.i;
    unsigned int r = (x >> 16) & 1u;
    x += 0x7fffu + r;                 // round-to-nearest-even
    return (ushort)(x >> 16);
}
__device__ __forceinline__ float rmax16(float v) {
#pragma unroll
    for (int off = 1; off < 16; off <<= 1) v = fmaxf(v, __shfl_xor(v, off, 64));
    return v;
}
__device__ __forceinline__ float rsum16(float v) {
#pragma unroll
    for (int off = 1; off < 16; off <<= 1) v += __shfl_xor(v, off, 64);
    return v;
}

__global__ __launch_bounds__(BDIM, 3) void star_agg_kernel(
    const float* __restrict__ hid,
    const int*   __restrict__ adj,
    const float* __restrict__ maskp,
    const float* __restrict__ a0p, const float* __restrict__ a1p,
    const float* __restrict__ a2p, const float* __restrict__ a3p,
    const float* __restrict__ q1p, const float* __restrict__ k1p,
    const float* __restrict__ q2p, const float* __restrict__ k2p,
    const float* __restrict__ wlp,
    float* __restrict__ outp)
{
    // sate in bf16 hi/lo split. Row stride 136 u16 = 272 B (16-B aligned,
    // 4-bank skew/row -> 2-way-max conflicts on b128 fragment reads).
    __shared__ __align__(16) ushort hb[Nc][136];
    __shared__ __align__(16) ushort hlo[Nc][136];
    __shared__ __align__(16) ushort Pb[Nc][72];   // attention probs bf16, stride 144 B
    __shared__ float aL[4][Dc];
    __shared__ float star_s[Dc];
    __shared__ float kk_s[Dc], qq_s[Dc];
    __shared__ float vv_s[Dc], ww_s[Dc];
    __shared__ float m_s[Nc];
    __shared__ float beta_s[Nc];
    __shared__ float star_part[4][Dc];

    const int b      = blockIdx.x;
    const int tid    = threadIdx.x;
    const int lane   = tid & 63;
    const int wv     = tid >> 6;
    const int lane15 = lane & 15;
    const int quad   = lane >> 4;

    // ---- stage: hidden -> hb/hlo (bf16 split), a -> aL, mask -> m_s
    {
        const float4* hp4 = (const float4*)(hid + (size_t)b * (Nc * Dc));
        for (int idx = tid; idx < (Nc * Dc) / 4; idx += BDIM) {
            const int r = idx >> 5;
            const int c = (idx & 31) * 4;
            const float4 v = hp4[idx];
            ushort4 hi4, lo4;
            hi4.x = f2bf(v.x); lo4.x = f2bf(v.x - bf2f(hi4.x));
            hi4.y = f2bf(v.y); lo4.y = f2bf(v.y - bf2f(hi4.y));
            hi4.z = f2bf(v.z); lo4.z = f2bf(v.z - bf2f(hi4.z));
            hi4.w = f2bf(v.w); lo4.w = f2bf(v.w - bf2f(hi4.w));
            *(ushort4*)&hb[r][c]  = hi4;
            *(ushort4*)&hlo[r][c] = lo4;
        }
        if (tid < 128) {
            const int t = tid >> 5, c4 = tid & 31;
            const float* ap = (t == 0) ? a0p : (t == 1) ? a1p : (t == 2) ? a2p : a3p;
            *(float4*)&aL[t][c4 * 4] = *(const float4*)&ap[c4 * 4];
        }
        if (tid < Nc) m_s[tid] = maskp[b * Nc + tid];
    }
    __syncthreads();

    // ---- star init: masked average
    if (tid < Dc) {
        float s = 0.f, ms = 0.f;
        for (int i = 0; i < Nc; ++i) {
            const float hv = bf2f(hb[i][tid]) + bf2f(hlo[i][tid]);
            s = fmaf(hv, m_s[i], s);
            ms += m_s[i];
        }
        star_s[tid] = s / ms;
    }
    __syncthreads();

    float s2[8][4];   // sate slab (C-layout), survives into the gate

    for (int step = 0; step < 2; ++step) {
        // ---- matvecs from star (alpha/beta precursors)
        if (tid < Dc) {
            const int c = tid;
            float s = 0.f;
            for (int d = 0; d < Dc; ++d) s = fmaf(star_s[d], k1p[d * Dc + c], s);
            kk_s[c] = s;
        } else {
            const int c = tid - Dc;
            float s = 0.f;
            for (int d = 0; d < Dc; ++d) s = fmaf(star_s[d], q2p[d * Dc + c], s);
            qq_s[c] = s;
        }
        __syncthreads();
        if (tid < Dc) {
            const int c = tid;
            float s = 0.f;
            for (int e4 = 0; e4 < Dc; e4 += 4) {
                const float4 qv = *(const float4*)&q1p[c * Dc + e4];
                s = fmaf(qv.w, kk_s[e4 + 3], fmaf(qv.z, kk_s[e4 + 2],
                    fmaf(qv.y, kk_s[e4 + 1], fmaf(qv.x, kk_s[e4], s))));
            }
            vv_s[c] = s * INV_SQRT_D;
        } else {
            const int c = tid - Dc;
            float s = 0.f;
            for (int e4 = 0; e4 < Dc; e4 += 4) {
                const float4 kv = *(const float4*)&k2p[c * Dc + e4];
                s = fmaf(kv.w, qq_s[e4 + 3], fmaf(kv.z, qq_s[e4 + 2],
                    fmaf(kv.y, qq_s[e4 + 1], fmaf(kv.x, qq_s[e4], s))));
            }
            ww_s[c] = s * INV_SQRT_D;
        }
        __syncthreads();

        // ---- Phase A: relation logits via split-bf16 MFMA.
        // Wave wv owns rows [wv*16, wv*16+16); computes all 4 E_t for 4 j-tiles.
        f32x4 eacc[4][4];   // [t][ntile]
#pragma unroll
        for (int t = 0; t < 4; ++t)
#pragma unroll
            for (int n = 0; n < 4; ++n) eacc[t][n] = (f32x4)0.f;

        const int arow = wv * 16 + lane15;
#pragma unroll
        for (int kc = 0; kc < 4; ++kc) {
            const int ko = kc * 32 + quad * 8;
            const bf16x8 hh = *(const bf16x8*)&hb[arow][ko];
            const bf16x8 hl = *(const bf16x8*)&hlo[arow][ko];
            float hx[8];
#pragma unroll
            for (int e = 0; e < 8; ++e)
                hx[e] = bf2f((ushort)hh[e]) + bf2f((ushort)hl[e]);
            bf16x8 Ahi[4], Alo[4];
#pragma unroll
            for (int t = 0; t < 4; ++t) {
                const float4 a0 = *(const float4*)&aL[t][ko];
                const float4 a1 = *(const float4*)&aL[t][ko + 4];
                const float av[8] = {a0.x, a0.y, a0.z, a0.w, a1.x, a1.y, a1.z, a1.w};
#pragma unroll
                for (int e = 0; e < 8; ++e) {
                    const float p = hx[e] * av[e];
                    const ushort ph = f2bf(p);
                    const ushort pl = f2bf(p - bf2f(ph));
                    Ahi[t][e] = (short)ph;
                    Alo[t][e] = (short)pl;
                }
            }
#pragma unroll
            for (int n = 0; n < 4; ++n) {
                const int brow = n * 16 + lane15;
                const bf16x8 Bh = *(const bf16x8*)&hb[brow][ko];
                const bf16x8 Bl = *(const bf16x8*)&hlo[brow][ko];
#pragma unroll
                for (int t = 0; t < 4; ++t) {
                    eacc[t][n] = MFMA16(Ahi[t], Bh, eacc[t][n]);
                    eacc[t][n] = MFMA16(Ahi[t], Bl, eacc[t][n]);
                    eacc[t][n] = MFMA16(Alo[t], Bh, eacc[t][n]);
                }
            }
        }

        // ---- selection by adj + leaky (static register indexing)
        float lg[4][4];   // [ntile][reg]
#pragma unroll
        for (int n = 0; n < 4; ++n) {
#pragma unroll
            for (int r = 0; r < 4; ++r) {
                const int i = wv * 16 + quad * 4 + r;
                const int j = n * 16 + lane15;
                const int t = adj[(size_t)b * 4096 + i * 64 + j];
                const float v0 = eacc[0][n][r], v1 = eacc[1][n][r];
                const float v2 = eacc[2][n][r], v3 = eacc[3][n][r];
                const float sel = (t == 1) ? v0 : (t == 2) ? v1 : (t == 3) ? v2 : v3;
                const float e = (t >= 1 && t <= 4) ? ((sel >= 0.f) ? sel : 0.2f * sel)
                                                   : NEG_BIG_F;
                lg[n][r] = e;
            }
        }

        // ---- in-register softmax over j (16 lanes x 4 ntiles) -> P (bf16 LDS)
#pragma unroll
        for (int r = 0; r < 4; ++r) {
            float mx = fmaxf(fmaxf(lg[0][r], lg[1][r]), fmaxf(lg[2][r], lg[3][r]));
            mx = rmax16(mx);
            float pr[4], s = 0.f;
#pragma unroll
            for (int n = 0; n < 4; ++n) { pr[n] = __expf(lg[n][r] - mx); s += pr[n]; }
            s = rsum16(s);
            const float inv = 1.f / s;
            const int irow = wv * 16 + quad * 4 + r;
#pragma unroll
            for (int n = 0; n < 4; ++n)
                Pb[irow][n * 16 + lane15] = f2bf(pr[n] * inv);
        }
        __syncthreads();

        // ---- Phase B: sate1 = P @ sate  (single-precision bf16 MFMA)
        f32x4 s1[8];
#pragma unroll
        for (int nd = 0; nd < 8; ++nd) s1[nd] = (f32x4)0.f;
#pragma unroll
        for (int kc2 = 0; kc2 < 2; ++kc2) {
            const int ko = kc2 * 32 + quad * 8;
            const bf16x8 Pa = *(const bf16x8*)&Pb[wv * 16 + lane15][ko];
#pragma unroll
            for (int nd = 0; nd < 8; ++nd) {
                const int dc = nd * 16 + lane15;
                bf16x8 Bf;
#pragma unroll
                for (int jj = 0; jj < 8; ++jj) Bf[jj] = (short)hb[ko + jj][dc];
                s1[nd] = MFMA16(Pa, Bf, s1[nd]);
            }
        }

        // ---- alpha blend: sate2 = (1-alpha)*sate1 + alpha*star
        float vvv[8], stv[8];
#pragma unroll
        for (int nt = 0; nt < 8; ++nt) {
            vvv[nt] = vv_s[nt * 16 + lane15];
            stv[nt] = star_s[nt * 16 + lane15];
        }
#pragma unroll
        for (int r = 0; r < 4; ++r) {
            float part = 0.f;
#pragma unroll
            for (int nt = 0; nt < 8; ++nt) part = fmaf(s1[nt][r], vvv[nt], part);
            const float al = rsum16(part);
#pragma unroll
            for (int nt = 0; nt < 8; ++nt)
                s2[nt][r] = (1.f - al) * s1[nt][r] + al * stv[nt];
        }

        // ---- beta logits (masked, finite sentinel)
        float www[8];
#pragma unroll
        for (int nt = 0; nt < 8; ++nt) www[nt] = ww_s[nt * 16 + lane15];
        float bm[4];
#pragma unroll
        for (int r = 0; r < 4; ++r) {
            float part = 0.f;
#pragma unroll
            for (int nt = 0; nt < 8; ++nt) part = fmaf(s2[nt][r], www[nt], part);
            const float bj = rsum16(part);
            const int j = wv * 16 + quad * 4 + r;
            bm[r] = (m_s[j] == 0.f) ? NEG_BIG_F : bj;
            if (lane15 == 0) beta_s[j] = bm[r];
        }
        __syncthreads();

        // ---- star = softmax(beta) @ sate2 : per-wave partials + sate2 -> LDS
        {
            float mx = NEG_BIG_F;
#pragma unroll
            for (int j4 = 0; j4 < 16; ++j4) {
                const float4 bv = *(const float4*)&beta_s[j4 * 4];
                mx = fmaxf(mx, fmaxf(fmaxf(bv.x, bv.y), fmaxf(bv.z, bv.w)));
            }
            float p[4];
#pragma unroll
            for (int r = 0; r < 4; ++r) p[r] = __expf(bm[r] - mx);
            float part[8];
#pragma unroll
            for (int nt = 0; nt < 8; ++nt) {
                float v = 0.f;
#pragma unroll
                for (int r = 0; r < 4; ++r) v = fmaf(p[r], s2[nt][r], v);
                v += __shfl_xor(v, 16, 64);
                v += __shfl_xor(v, 32, 64);
                part[nt] = v;
            }
            if (lane < 16) {
#pragma unroll
                for (int nt = 0; nt < 8; ++nt)
                    star_part[wv][nt * 16 + lane15] = part[nt];
            }
            // sate2 -> hb/hlo (for next step's MFMA operands / gate)
#pragma unroll
            for (int nt = 0; nt < 8; ++nt) {
#pragma unroll
                for (int r = 0; r < 4; ++r) {
                    const float v = s2[nt][r];
                    const ushort hi = f2bf(v);
                    const ushort lo = f2bf(v - bf2f(hi));
                    const int row = wv * 16 + quad * 4 + r;
                    const int c   = nt * 16 + lane15;
                    hb[row][c]  = hi;
                    hlo[row][c] = lo;
                }
            }
        }
        __syncthreads();
        if (tid < Dc) {
            float mx = NEG_BIG_F;
            for (int j = 0; j < Nc; ++j) mx = fmaxf(mx, beta_s[j]);
            float S = 0.f;
            for (int j = 0; j < Nc; ++j) S += __expf(beta_s[j] - mx);
            const float tot = star_part[0][tid] + star_part[1][tid]
                            + star_part[2][tid] + star_part[3][tid];
            star_s[tid] = tot / S;
        }
        __syncthreads();
    }

    // ---- gate GEMM: logits = [hidden, sate2] @ W^T via MFMA
    f32x4 g[8];
#pragma unroll
    for (int n = 0; n < 8; ++n) g[n] = (f32x4)0.f;
    const int arow_g = wv * 16 + lane15;
    const float* hrowA = hid + ((size_t)b * 64 + arow_g) * Dc;
#pragma unroll
    for (int kc = 0; kc < 8; ++kc) {
        bf16x8 Ah, Al;
        const bool has_lo = (kc >= 4);
        if (!has_lo) {
            const int co = kc * 32 + quad * 8;
            const float4 h0 = *(const float4*)&hrowA[co];
            const float4 h1 = *(const float4*)&hrowA[co + 4];
            const float hv[8] = {h0.x, h0.y, h0.z, h0.w, h1.x, h1.y, h1.z, h1.w};
#pragma unroll
            for (int e = 0; e < 8; ++e) Ah[e] = (short)f2bf(hv[e]);
        } else {
            const int co = (kc - 4) * 32 + quad * 8;
            Ah = *(const bf16x8*)&hb[arow_g][co];
            Al = *(const bf16x8*)&hlo[arow_g][co];
        }
#pragma unroll
        for (int n = 0; n < 8; ++n) {
            const int orow = n * 16 + lane15;
            const float* wr = wlp + orow * 256 + kc * 32 + quad * 8;
            const float4 w0 = *(const float4*)&wr[0];
            const float4 w1 = *(const float4*)&wr[4];
            const float wvv[8] = {w0.x, w0.y, w0.z, w0.w, w1.x, w1.y, w1.z, w1.w};
            bf16x8 Bf;
#pragma unroll
            for (int e = 0; e < 8; ++e) Bf[e] = (short)f2bf(wvv[e]);
            g[n] = MFMA16(Ah, Bf, g[n]);
            if (has_lo) g[n] = MFMA16(Al, Bf, g[n]);
        }
    }

    // ---- epilogue: out = g*hidden + (1-g)*sate2 ; star output
#pragma unroll
    for (int n = 0; n < 8; ++n) {
#pragma unroll
        for (int r = 0; r < 4; ++r) {
            const int i = wv * 16 + quad * 4 + r;
            const int o = n * 16 + lane15;
            const float gg = 1.f / (1.f + __expf(-g[n][r]));
            const float hv = hid[((size_t)b * 64 + i) * Dc + o];
            outp[((size_t)b * 64 + i) * Dc + o] = gg * hv + (1.f - gg) * s2[n][r];
        }
    }
    if (tid < Dc)
        outp[(size_t)Bc * Nc * Dc + (size_t)b * Dc + tid] = star_s[tid];
}

extern "C" void kernel_launch(void* const* d_in, const int* in_sizes, int n_in,
                              void* d_out, int out_size, void* d_ws, size_t ws_size,
                              hipStream_t stream) {
    const float* hid  = (const float*)d_in[0];
    const int*   adj  = (const int*)d_in[1];
    const float* mask = (const float*)d_in[2];
    const float* a0   = (const float*)d_in[3];
    const float* a1   = (const float*)d_in[4];
    const float* a2   = (const float*)d_in[5];
    const float* a3   = (const float*)d_in[6];
    const float* q1   = (const float*)d_in[7];
    const float* k1   = (const float*)d_in[8];
    const float* q2   = (const float*)d_in[9];
    const float* k2   = (const float*)d_in[10];
    const float* wl   = (const float*)d_in[11];
    float* out = (float*)d_out;

    star_agg_kernel<<<Bc, BDIM, 0, stream>>>(hid, adj, mask, a0, a1, a2, a3,
                                             q1, k1, q2, k2, wl, out);
}